// Round 7
// baseline (152.269 us; speedup 1.0000x reference)
//
#include <hip/hip_runtime.h>

// DPQ embedding, MI355X. N=131072 tokens, EMB=128, D=8 subspaces x SUB=16, K=128 codes.
// Pipeline:
//  k1_stats:  gather x rows, accumulate per-block moment stats (G, Sx, h, Sn, S2)
//  k2a/k2b:   deterministic two-stage tree-reduce of block partials (in-place)
//  k3_final:  stats + centroids -> alpha[k], beta[d][k]  (BN folded into affine score)
//  k4_main:   8 tokens/thread, one d/block, LDS-broadcast centroids with EXPLICIT
//             one-k-ahead register prefetch (issue k+1 reads, compute k, rotate):
//             the lgkmcnt wait lands after 288 cyc of FMA issue instead of before.
// History: R2 88us; R3 103us (SMEM 1 stream); R4 126us (SMEM 2 streams, drain);
// R5 123us (DS-issue bound, 9 reads/2 token-d); R6 115us (DS amortized 14x but
// latency-exposed: 2 waves/SIMD grid limit, VALUBusy 39%, busy-time == VALU
// work estimate -> pure exposed LDS latency. T>=6 required to stay off the LDS
// pipe, so more waves impossible -> hide latency in-wave via rotation).

constexpr int NTOK = 131072;   // 1024*128
constexpr int ST   = 2320;     // stats stride (2312 used, padded)
constexpr float EPS = 0.001f;

// stats layout: G: d*256 + s*16 + s'  (2048)
//               Sx: 2048 + d*16 + s   (128)
//               h : 2176 + d*16 + s   (128)
//               S2: 2304 + d          (8)    -> 2312 total

__global__ __launch_bounds__(256) void k1_stats(const int* __restrict__ ids,
                                                const float* __restrict__ wemb,
                                                float* __restrict__ partials,
                                                int tpb)
{
    __shared__ float xs[32][132];   // 32 tokens x 128 floats, padded to 132
    __shared__ float nrm[32][8];
    const int t = threadIdx.x;
    const int b = blockIdx.x;

    float g[4][4];
#pragma unroll
    for (int i = 0; i < 4; ++i)
#pragma unroll
        for (int j = 0; j < 4; ++j) g[i][j] = 0.f;
    float sx = 0.f, hh = 0.f, s2 = 0.f;

    const int d_g = t >> 4;                 // t<128: Gram task (d, 4x4 tile)
    const int r0  = ((t >> 2) & 3) << 2;
    const int c0  = (t & 3) << 2;
    const int u   = t & 127;                // t>=128: (d,s) task
    const int d_s = u >> 4;
    const int s_s = u & 15;

    const int nchunks = tpb >> 5;
    for (int ch = 0; ch < nchunks; ++ch) {
        const int n0 = b * tpb + ch * 32;
        // ---- load 32 token rows (coalesced: 32 lanes x float4 = one 512B row) ----
#pragma unroll
        for (int rep = 0; rep < 4; ++rep) {
            int i = t + rep * 256;
            int n = i >> 5, f = i & 31;
            int id = ids[n0 + n];
            float4 v = *(const float4*)(wemb + (size_t)id * 128 + f * 4);
            *(float4*)(&xs[n][f * 4]) = v;
        }
        __syncthreads();
        // ---- per-(n,d) norms: 256 threads = 32x8 ----
        {
            int n = t >> 3, dd = t & 7;
            const float* xp = &xs[n][dd * 16];
            float4 a = *(const float4*)(xp);
            float4 bq = *(const float4*)(xp + 4);
            float4 c = *(const float4*)(xp + 8);
            float4 dq = *(const float4*)(xp + 12);
            float acc = a.x*a.x + a.y*a.y + a.z*a.z + a.w*a.w;
            acc += bq.x*bq.x + bq.y*bq.y + bq.z*bq.z + bq.w*bq.w;
            acc += c.x*c.x + c.y*c.y + c.z*c.z + c.w*c.w;
            acc += dq.x*dq.x + dq.y*dq.y + dq.z*dq.z + dq.w*dq.w;
            nrm[n][dd] = acc;
        }
        __syncthreads();
        // ---- accumulate stats over the chunk ----
        if (t < 128) {
            for (int n = 0; n < 32; ++n) {
                const float* xp = &xs[n][d_g * 16];
                float4 av = *(const float4*)(xp + r0);
                float4 bv = *(const float4*)(xp + c0);
                float aa[4] = {av.x, av.y, av.z, av.w};
                float bb[4] = {bv.x, bv.y, bv.z, bv.w};
#pragma unroll
                for (int i = 0; i < 4; ++i)
#pragma unroll
                    for (int j = 0; j < 4; ++j)
                        g[i][j] = fmaf(aa[i], bb[j], g[i][j]);
            }
        } else {
            for (int n = 0; n < 32; ++n) {
                float xv = xs[n][d_s * 16 + s_s];
                float nv = nrm[n][d_s];
                sx += xv;
                hh = fmaf(nv, xv, hh);
                if (s_s == 0) s2 = fmaf(nv, nv, s2);
            }
        }
        __syncthreads();
    }
    float* pb = partials + (size_t)b * ST;
    if (t < 128) {
        const int base = d_g * 256;
#pragma unroll
        for (int i = 0; i < 4; ++i)
#pragma unroll
            for (int j = 0; j < 4; ++j)
                pb[base + (r0 + i) * 16 + (c0 + j)] = g[i][j];
    } else {
        pb[2048 + d_s * 16 + s_s] = sx;
        pb[2176 + d_s * 16 + s_s] = hh;
        if (s_s == 0) pb[2304 + d_s] = s2;
    }
}

// ---- stage A: fold nb blocks down to 32, in place. grid (10, 32). ----
__global__ __launch_bounds__(256) void k2a_reduce(float* __restrict__ partials, int nb)
{
    const int idx = blockIdx.x * 256 + threadIdx.x;
    if (idx >= 2312) return;
    const int y = blockIdx.y;          // 0..31
    float acc[8] = {0.f, 0.f, 0.f, 0.f, 0.f, 0.f, 0.f, 0.f};
    int b = y;
    while (b + 7 * 32 < nb) {
#pragma unroll
        for (int u = 0; u < 8; ++u)
            acc[u] += partials[(size_t)(b + u * 32) * ST + idx];
        b += 8 * 32;
    }
    while (b < nb) { acc[0] += partials[(size_t)b * ST + idx]; b += 32; }
    float s = ((acc[0] + acc[1]) + (acc[2] + acc[3]))
            + ((acc[4] + acc[5]) + (acc[6] + acc[7]));
    partials[(size_t)y * ST + idx] = s;
}

// ---- stage B: sum the 32 survivors (L2-resident, fully unrolled). grid 10. ----
__global__ __launch_bounds__(256) void k2b_reduce(const float* __restrict__ partials,
                                                  float* __restrict__ stats)
{
    const int idx = blockIdx.x * 256 + threadIdx.x;
    if (idx >= 2312) return;
    float acc[8] = {0.f, 0.f, 0.f, 0.f, 0.f, 0.f, 0.f, 0.f};
#pragma unroll
    for (int j = 0; j < 4; ++j)
#pragma unroll
        for (int u = 0; u < 8; ++u)
            acc[u] += partials[(size_t)(j * 8 + u) * ST + idx];
    stats[idx] = ((acc[0] + acc[1]) + (acc[2] + acc[3]))
               + ((acc[4] + acc[5]) + (acc[6] + acc[7]));
}

__global__ __launch_bounds__(128) void k3_final(const float* __restrict__ stats,
                                                const float* __restrict__ centroids,
                                                float2* __restrict__ ab)
{
    __shared__ float st[2312];
    const int t = threadIdx.x;
    for (int i = t; i < 2312; i += 128) st[i] = stats[i];
    __syncthreads();
    const int k = t;   // 128 threads, one per code

    double Sn[8], Sn_tot = 0.0, S2_tot = 0.0;
#pragma unroll
    for (int d = 0; d < 8; ++d) {
        double s = 0.0;
        for (int ss = 0; ss < 16; ++ss) s += (double)st[d * 256 + ss * 17];
        Sn[d] = s; Sn_tot += s;
        S2_tot += (double)st[2304 + d];
    }
    double sr = -Sn_tot, sr2 = S2_tot;
    double ncd[8];
    for (int d = 0; d < 8; ++d) {
        const float* cp = centroids + d * 2048 + k * 16;
        float cv[16];
#pragma unroll
        for (int s = 0; s < 16; ++s) cv[s] = cp[s];
        double nc = 0, cdSx = 0, ch = 0, cGc = 0;
        for (int s = 0; s < 16; ++s) {
            nc   += (double)cv[s] * cv[s];
            cdSx += (double)cv[s] * st[2048 + d * 16 + s];
            ch   += (double)cv[s] * st[2176 + d * 16 + s];
            double rd = 0;
            for (int s2i = 0; s2i < 16; ++s2i)
                rd += (double)st[d * 256 + s * 16 + s2i] * cv[s2i];
            cGc += (double)cv[s] * rd;
        }
        ncd[d] = nc;
        sr  += 2.0 * cdSx - (double)NTOK * nc;
        sr2 += 4.0 * cGc + (double)NTOK * nc * nc + 2.0 * nc * Sn[d]
               - 4.0 * ch - 4.0 * nc * cdSx;
    }
    const double M = (double)NTOK * 8.0;
    double mean = sr / M;
    double var  = sr2 / M - mean * mean;
    float alpha = (float)(1.0 / sqrt(var + (double)EPS));
#pragma unroll
    for (int d = 0; d < 8; ++d) {
        float beta = (float)((double)alpha * (-ncd[d] - mean));
        ab[d * 128 + k] = make_float2(2.f * alpha, beta);
    }
}

// 8 tokens/thread, one d per blockIdx.y, 128-thread blocks (2 waves).
// Software-pipelined k-loop: issue k+1's 5 uniform LDS reads into `n*`
// registers, compute k's 8x17 FMAs with `c*`, rotate. The compiler places the
// lgkmcnt wait at the rotation (first use of n*), i.e. AFTER the FMA burst, so
// the ~120cyc LDS latency hides under 288 cyc of VALU issue even at the
// grid-imposed 2 waves/SIMD.
__global__ __launch_bounds__(128) void k4_main(const int* __restrict__ ids,
                                               const float* __restrict__ wemb,
                                               const float* __restrict__ centroids,
                                               const float2* __restrict__ ab,
                                               float* __restrict__ out)
{
    __shared__ float  cs[128 * 16];   // 8KB: centroids for this d
    __shared__ float2 gbs[128];       // (2*alpha, beta)

    const int t = threadIdx.x;        // 0..127
    const int d = blockIdx.y;
    const float* cd = centroids + (size_t)d * 2048;

    // stage: 2048 floats = 512 float4 -> 4 per thread; 1 gb each
#pragma unroll
    for (int i = 0; i < 4; ++i)
        ((float4*)cs)[t + i * 128] = ((const float4*)cd)[t + i * 128];
    gbs[t] = ab[(size_t)d * 128 + t];

    const int nbase = blockIdx.x * 1024 + t;   // 8 tokens, stride 128
    float x[8][16];
    float nx[8], best[8];
    int   code[8];
#pragma unroll
    for (int j = 0; j < 8; ++j) {
        const int n = nbase + j * 128;
        const float* xp = wemb + (size_t)ids[n] * 128 + d * 16;
#pragma unroll
        for (int q = 0; q < 16; q += 4) {
            float4 v = *(const float4*)(xp + q);
            x[j][q] = v.x; x[j][q + 1] = v.y; x[j][q + 2] = v.z; x[j][q + 3] = v.w;
        }
        float s = 0.f;
#pragma unroll
        for (int q = 0; q < 16; ++q) s = fmaf(x[j][q], x[j][q], s);
        nx[j] = -0.5f * s;             // score = 2a*(dot - nx/2) + beta
        best[j] = -3.4e38f;
        code[j] = 0;
    }

    __syncthreads();

    // ---- prologue: read k=0 ----
    float4 c0 = *(const float4*)(&cs[0]);
    float4 c1 = *(const float4*)(&cs[4]);
    float4 c2 = *(const float4*)(&cs[8]);
    float4 c3 = *(const float4*)(&cs[12]);
    float2 g  = gbs[0];

#pragma unroll 4
    for (int k = 0; k < 128; ++k) {
        // ---- issue k+1 reads first (wrap reads k=0 again; 1 wasted iter) ----
        const int kn = (k + 1) & 127;
        const float4 m0 = *(const float4*)(&cs[kn * 16 + 0]);
        const float4 m1 = *(const float4*)(&cs[kn * 16 + 4]);
        const float4 m2 = *(const float4*)(&cs[kn * 16 + 8]);
        const float4 m3 = *(const float4*)(&cs[kn * 16 + 12]);
        const float2 mg = gbs[kn];
        // ---- compute k with current registers ----
#pragma unroll
        for (int j = 0; j < 8; ++j) {
            float acc = nx[j];
            acc = fmaf(c0.x, x[j][0],  acc);
            acc = fmaf(c0.y, x[j][1],  acc);
            acc = fmaf(c0.z, x[j][2],  acc);
            acc = fmaf(c0.w, x[j][3],  acc);
            acc = fmaf(c1.x, x[j][4],  acc);
            acc = fmaf(c1.y, x[j][5],  acc);
            acc = fmaf(c1.z, x[j][6],  acc);
            acc = fmaf(c1.w, x[j][7],  acc);
            acc = fmaf(c2.x, x[j][8],  acc);
            acc = fmaf(c2.y, x[j][9],  acc);
            acc = fmaf(c2.z, x[j][10], acc);
            acc = fmaf(c2.w, x[j][11], acc);
            acc = fmaf(c3.x, x[j][12], acc);
            acc = fmaf(c3.y, x[j][13], acc);
            acc = fmaf(c3.z, x[j][14], acc);
            acc = fmaf(c3.w, x[j][15], acc);
            float sc = fmaf(g.x, acc, g.y);
            bool p = sc > best[j];         // strict > keeps FIRST max (argmax tie rule)
            best[j] = p ? sc : best[j];
            code[j] = p ? k : code[j];
        }
        // ---- rotate (register-renamed by unroll; lgkmcnt wait lands here) ----
        c0 = m0; c1 = m1; c2 = m2; c3 = m3; g = mg;
    }

#pragma unroll
    for (int j = 0; j < 8; ++j) {
        const int n = nbase + j * 128;
        const float* cw = cd + code[j] * 16;   // global, L1-hot 8KB set
        float* op = out + (size_t)n * 128 + d * 16;
#pragma unroll
        for (int q = 0; q < 16; q += 4) {
            float4 cv = *(const float4*)(cw + q);
            float4 o;
            // match reference: out = x + (c - x) in fp32 (not just c)
            o.x = x[j][q + 0] + (cv.x - x[j][q + 0]);
            o.y = x[j][q + 1] + (cv.y - x[j][q + 1]);
            o.z = x[j][q + 2] + (cv.z - x[j][q + 2]);
            o.w = x[j][q + 3] + (cv.w - x[j][q + 3]);
            *(float4*)(op + q) = o;
        }
    }
}

extern "C" void kernel_launch(void* const* d_in, const int* in_sizes, int n_in,
                              void* d_out, int out_size, void* d_ws, size_t ws_size,
                              hipStream_t stream)
{
    const int* ids    = (const int*)d_in[0];
    const float* wemb = (const float*)d_in[1];
    const float* cent = (const float*)d_in[2];
    float* out = (float*)d_out;
    float* ws  = (float*)d_ws;

    // choose pass-1 block count by available workspace
    int p1b = 1024;
    if (ws_size < ((size_t)1024 * ST + 2320 + 2048) * 4) p1b = 512;
    if (ws_size < ((size_t)512  * ST + 2320 + 2048) * 4) p1b = 256;
    if (ws_size < ((size_t)256  * ST + 2320 + 2048) * 4) p1b = 128;
    const int tpb = NTOK / p1b;

    float* partials = ws;
    float* stats    = ws + (size_t)p1b * ST;
    float2* ab      = (float2*)(stats + 2320);

    hipLaunchKernelGGL(k1_stats,   dim3(p1b),     dim3(256), 0, stream, ids, wemb, partials, tpb);
    hipLaunchKernelGGL(k2a_reduce, dim3(10, 32),  dim3(256), 0, stream, partials, p1b);
    hipLaunchKernelGGL(k2b_reduce, dim3(10),      dim3(256), 0, stream, partials, stats);
    hipLaunchKernelGGL(k3_final,   dim3(1),       dim3(128), 0, stream, stats, cent, ab);
    hipLaunchKernelGGL(k4_main,    dim3(128, 8),  dim3(128), 0, stream, ids, wemb, cent, ab, out);
}

// Round 8
// 147.714 us; speedup vs baseline: 1.0308x; 1.0308x over previous
//
#include <hip/hip_runtime.h>

// DPQ embedding, MI355X. N=131072 tokens, EMB=128, D=8 subspaces x SUB=16, K=128 codes.
// Pipeline:
//  k1_stats:  gather x rows, accumulate per-block moment stats (G, Sx, h, Sn, S2)
//  k2a/k2b:   deterministic two-stage tree-reduce of block partials (in-place)
//  k3_final:  stats + centroids -> alpha[k], beta[d][k]  (BN folded into affine score)
//  k4_main:   4 tokens/thread, one d/block, 256-thr blocks -> 4 waves/SIMD.
//             Centroids broadcast from LDS (uniform ds_read_b128); FMAs directly
//             on float4 components. Latency hidden by WAVE parallelism, not
//             in-wave pipelining.
// History: R2 88us (T=4, 4 w/SIMD, VALUBusy 55% -- best structure, had v_mov
// unpack storms); R5 123us (DS-issue bound); R6 115us (T=8 -> only 2 w/SIMD,
// VALUBusy 39%, pure exposed LDS latency); R7 123us (manual prefetch dead on
// arrival: x[8][16]=128 VGPR left no regs to hold in-flight values; VGPR=160
// cap re-serialized the loop). Lesson: the T knob trades waves/SIMD (latency
// hiding) against DS amortization; T=4 is the balance point and frees VGPRs.

constexpr int NTOK = 131072;   // 1024*128
constexpr int ST   = 2320;     // stats stride (2312 used, padded)
constexpr float EPS = 0.001f;

// stats layout: G: d*256 + s*16 + s'  (2048)
//               Sx: 2048 + d*16 + s   (128)
//               h : 2176 + d*16 + s   (128)
//               S2: 2304 + d          (8)    -> 2312 total

__global__ __launch_bounds__(256) void k1_stats(const int* __restrict__ ids,
                                                const float* __restrict__ wemb,
                                                float* __restrict__ partials,
                                                int tpb)
{
    __shared__ float xs[32][132];   // 32 tokens x 128 floats, padded to 132
    __shared__ float nrm[32][8];
    const int t = threadIdx.x;
    const int b = blockIdx.x;

    float g[4][4];
#pragma unroll
    for (int i = 0; i < 4; ++i)
#pragma unroll
        for (int j = 0; j < 4; ++j) g[i][j] = 0.f;
    float sx = 0.f, hh = 0.f, s2 = 0.f;

    const int d_g = t >> 4;                 // t<128: Gram task (d, 4x4 tile)
    const int r0  = ((t >> 2) & 3) << 2;
    const int c0  = (t & 3) << 2;
    const int u   = t & 127;                // t>=128: (d,s) task
    const int d_s = u >> 4;
    const int s_s = u & 15;

    const int nchunks = tpb >> 5;
    for (int ch = 0; ch < nchunks; ++ch) {
        const int n0 = b * tpb + ch * 32;
        // ---- load 32 token rows (coalesced: 32 lanes x float4 = one 512B row) ----
#pragma unroll
        for (int rep = 0; rep < 4; ++rep) {
            int i = t + rep * 256;
            int n = i >> 5, f = i & 31;
            int id = ids[n0 + n];
            float4 v = *(const float4*)(wemb + (size_t)id * 128 + f * 4);
            *(float4*)(&xs[n][f * 4]) = v;
        }
        __syncthreads();
        // ---- per-(n,d) norms: 256 threads = 32x8 ----
        {
            int n = t >> 3, dd = t & 7;
            const float* xp = &xs[n][dd * 16];
            float4 a = *(const float4*)(xp);
            float4 bq = *(const float4*)(xp + 4);
            float4 c = *(const float4*)(xp + 8);
            float4 dq = *(const float4*)(xp + 12);
            float acc = a.x*a.x + a.y*a.y + a.z*a.z + a.w*a.w;
            acc += bq.x*bq.x + bq.y*bq.y + bq.z*bq.z + bq.w*bq.w;
            acc += c.x*c.x + c.y*c.y + c.z*c.z + c.w*c.w;
            acc += dq.x*dq.x + dq.y*dq.y + dq.z*dq.z + dq.w*dq.w;
            nrm[n][dd] = acc;
        }
        __syncthreads();
        // ---- accumulate stats over the chunk ----
        if (t < 128) {
            for (int n = 0; n < 32; ++n) {
                const float* xp = &xs[n][d_g * 16];
                float4 av = *(const float4*)(xp + r0);
                float4 bv = *(const float4*)(xp + c0);
                float aa[4] = {av.x, av.y, av.z, av.w};
                float bb[4] = {bv.x, bv.y, bv.z, bv.w};
#pragma unroll
                for (int i = 0; i < 4; ++i)
#pragma unroll
                    for (int j = 0; j < 4; ++j)
                        g[i][j] = fmaf(aa[i], bb[j], g[i][j]);
            }
        } else {
            for (int n = 0; n < 32; ++n) {
                float xv = xs[n][d_s * 16 + s_s];
                float nv = nrm[n][d_s];
                sx += xv;
                hh = fmaf(nv, xv, hh);
                if (s_s == 0) s2 = fmaf(nv, nv, s2);
            }
        }
        __syncthreads();
    }
    float* pb = partials + (size_t)b * ST;
    if (t < 128) {
        const int base = d_g * 256;
#pragma unroll
        for (int i = 0; i < 4; ++i)
#pragma unroll
            for (int j = 0; j < 4; ++j)
                pb[base + (r0 + i) * 16 + (c0 + j)] = g[i][j];
    } else {
        pb[2048 + d_s * 16 + s_s] = sx;
        pb[2176 + d_s * 16 + s_s] = hh;
        if (s_s == 0) pb[2304 + d_s] = s2;
    }
}

// ---- stage A: fold nb blocks down to 32, in place. grid (10, 32). ----
__global__ __launch_bounds__(256) void k2a_reduce(float* __restrict__ partials, int nb)
{
    const int idx = blockIdx.x * 256 + threadIdx.x;
    if (idx >= 2312) return;
    const int y = blockIdx.y;          // 0..31
    float acc[8] = {0.f, 0.f, 0.f, 0.f, 0.f, 0.f, 0.f, 0.f};
    int b = y;
    while (b + 7 * 32 < nb) {
#pragma unroll
        for (int u = 0; u < 8; ++u)
            acc[u] += partials[(size_t)(b + u * 32) * ST + idx];
        b += 8 * 32;
    }
    while (b < nb) { acc[0] += partials[(size_t)b * ST + idx]; b += 32; }
    float s = ((acc[0] + acc[1]) + (acc[2] + acc[3]))
            + ((acc[4] + acc[5]) + (acc[6] + acc[7]));
    partials[(size_t)y * ST + idx] = s;
}

// ---- stage B: sum the 32 survivors (L2-resident, fully unrolled). grid 10. ----
__global__ __launch_bounds__(256) void k2b_reduce(const float* __restrict__ partials,
                                                  float* __restrict__ stats)
{
    const int idx = blockIdx.x * 256 + threadIdx.x;
    if (idx >= 2312) return;
    float acc[8] = {0.f, 0.f, 0.f, 0.f, 0.f, 0.f, 0.f, 0.f};
#pragma unroll
    for (int j = 0; j < 4; ++j)
#pragma unroll
        for (int u = 0; u < 8; ++u)
            acc[u] += partials[(size_t)(j * 8 + u) * ST + idx];
    stats[idx] = ((acc[0] + acc[1]) + (acc[2] + acc[3]))
               + ((acc[4] + acc[5]) + (acc[6] + acc[7]));
}

__global__ __launch_bounds__(128) void k3_final(const float* __restrict__ stats,
                                                const float* __restrict__ centroids,
                                                float2* __restrict__ ab)
{
    __shared__ float st[2312];
    const int t = threadIdx.x;
    for (int i = t; i < 2312; i += 128) st[i] = stats[i];
    __syncthreads();
    const int k = t;   // 128 threads, one per code

    double Sn[8], Sn_tot = 0.0, S2_tot = 0.0;
#pragma unroll
    for (int d = 0; d < 8; ++d) {
        double s = 0.0;
        for (int ss = 0; ss < 16; ++ss) s += (double)st[d * 256 + ss * 17];
        Sn[d] = s; Sn_tot += s;
        S2_tot += (double)st[2304 + d];
    }
    double sr = -Sn_tot, sr2 = S2_tot;
    double ncd[8];
    for (int d = 0; d < 8; ++d) {
        const float* cp = centroids + d * 2048 + k * 16;
        float cv[16];
#pragma unroll
        for (int s = 0; s < 16; ++s) cv[s] = cp[s];
        double nc = 0, cdSx = 0, ch = 0, cGc = 0;
        for (int s = 0; s < 16; ++s) {
            nc   += (double)cv[s] * cv[s];
            cdSx += (double)cv[s] * st[2048 + d * 16 + s];
            ch   += (double)cv[s] * st[2176 + d * 16 + s];
            double rd = 0;
            for (int s2i = 0; s2i < 16; ++s2i)
                rd += (double)st[d * 256 + s * 16 + s2i] * cv[s2i];
            cGc += (double)cv[s] * rd;
        }
        ncd[d] = nc;
        sr  += 2.0 * cdSx - (double)NTOK * nc;
        sr2 += 4.0 * cGc + (double)NTOK * nc * nc + 2.0 * nc * Sn[d]
               - 4.0 * ch - 4.0 * nc * cdSx;
    }
    const double M = (double)NTOK * 8.0;
    double mean = sr / M;
    double var  = sr2 / M - mean * mean;
    float alpha = (float)(1.0 / sqrt(var + (double)EPS));
#pragma unroll
    for (int d = 0; d < 8; ++d) {
        float beta = (float)((double)alpha * (-ncd[d] - mean));
        ab[d * 128 + k] = make_float2(2.f * alpha, beta);
    }
}

// 4 tokens/thread, one d per blockIdx.y, 256-thread blocks (4 waves).
// 4096 waves total = 4 waves/SIMD; x[4][16]=64 VGPR leaves ~40 free regs so the
// compiler can software-pipeline the 5 uniform LDS reads per k across unrolled
// iterations. Per SIMD per k: VALU demand ~592 cyc >> LDS latency+issue.
__global__ __launch_bounds__(256) void k4_main(const int* __restrict__ ids,
                                               const float* __restrict__ wemb,
                                               const float* __restrict__ centroids,
                                               const float2* __restrict__ ab,
                                               float* __restrict__ out)
{
    __shared__ float  cs[128 * 16];   // 8KB: centroids for this d
    __shared__ float2 gbs[128];       // (2*alpha, beta)

    const int t = threadIdx.x;        // 0..255
    const int d = blockIdx.y;
    const float* cd = centroids + (size_t)d * 2048;

    // stage: 2048 floats = 512 float4 -> 2 per thread; gb for t<128
#pragma unroll
    for (int i = 0; i < 2; ++i)
        ((float4*)cs)[t + i * 256] = ((const float4*)cd)[t + i * 256];
    if (t < 128) gbs[t] = ab[(size_t)d * 128 + t];

    const int nbase = blockIdx.x * 1024 + t;   // 4 tokens, stride 256
    float x[4][16];
    float nx[4], best[4];
    int   code[4];
#pragma unroll
    for (int j = 0; j < 4; ++j) {
        const int n = nbase + j * 256;
        const float* xp = wemb + (size_t)ids[n] * 128 + d * 16;
#pragma unroll
        for (int q = 0; q < 16; q += 4) {
            float4 v = *(const float4*)(xp + q);
            x[j][q] = v.x; x[j][q + 1] = v.y; x[j][q + 2] = v.z; x[j][q + 3] = v.w;
        }
        float s = 0.f;
#pragma unroll
        for (int q = 0; q < 16; ++q) s = fmaf(x[j][q], x[j][q], s);
        nx[j] = -0.5f * s;             // score = 2a*(dot - nx/2) + beta
        best[j] = -3.4e38f;
        code[j] = 0;
    }

    __syncthreads();

#pragma unroll 4
    for (int k = 0; k < 128; ++k) {
        // wave-uniform broadcast reads: 4x ds_read_b128 + 1 ds_read_b64
        const float4 c0 = *(const float4*)(&cs[k * 16 + 0]);
        const float4 c1 = *(const float4*)(&cs[k * 16 + 4]);
        const float4 c2 = *(const float4*)(&cs[k * 16 + 8]);
        const float4 c3 = *(const float4*)(&cs[k * 16 + 12]);
        const float2 g  = gbs[k];
#pragma unroll
        for (int j = 0; j < 4; ++j) {
            float acc = nx[j];
            acc = fmaf(c0.x, x[j][0],  acc);
            acc = fmaf(c0.y, x[j][1],  acc);
            acc = fmaf(c0.z, x[j][2],  acc);
            acc = fmaf(c0.w, x[j][3],  acc);
            acc = fmaf(c1.x, x[j][4],  acc);
            acc = fmaf(c1.y, x[j][5],  acc);
            acc = fmaf(c1.z, x[j][6],  acc);
            acc = fmaf(c1.w, x[j][7],  acc);
            acc = fmaf(c2.x, x[j][8],  acc);
            acc = fmaf(c2.y, x[j][9],  acc);
            acc = fmaf(c2.z, x[j][10], acc);
            acc = fmaf(c2.w, x[j][11], acc);
            acc = fmaf(c3.x, x[j][12], acc);
            acc = fmaf(c3.y, x[j][13], acc);
            acc = fmaf(c3.z, x[j][14], acc);
            acc = fmaf(c3.w, x[j][15], acc);
            float sc = fmaf(g.x, acc, g.y);
            bool p = sc > best[j];         // strict > keeps FIRST max (argmax tie rule)
            best[j] = p ? sc : best[j];
            code[j] = p ? k : code[j];
        }
    }

#pragma unroll
    for (int j = 0; j < 4; ++j) {
        const int n = nbase + j * 256;
        const float* cw = cd + code[j] * 16;   // global, L1-hot 8KB set
        float* op = out + (size_t)n * 128 + d * 16;
#pragma unroll
        for (int q = 0; q < 16; q += 4) {
            float4 cv = *(const float4*)(cw + q);
            float4 o;
            // match reference: out = x + (c - x) in fp32 (not just c)
            o.x = x[j][q + 0] + (cv.x - x[j][q + 0]);
            o.y = x[j][q + 1] + (cv.y - x[j][q + 1]);
            o.z = x[j][q + 2] + (cv.z - x[j][q + 2]);
            o.w = x[j][q + 3] + (cv.w - x[j][q + 3]);
            *(float4*)(op + q) = o;
        }
    }
}

extern "C" void kernel_launch(void* const* d_in, const int* in_sizes, int n_in,
                              void* d_out, int out_size, void* d_ws, size_t ws_size,
                              hipStream_t stream)
{
    const int* ids    = (const int*)d_in[0];
    const float* wemb = (const float*)d_in[1];
    const float* cent = (const float*)d_in[2];
    float* out = (float*)d_out;
    float* ws  = (float*)d_ws;

    // choose pass-1 block count by available workspace
    int p1b = 1024;
    if (ws_size < ((size_t)1024 * ST + 2320 + 2048) * 4) p1b = 512;
    if (ws_size < ((size_t)512  * ST + 2320 + 2048) * 4) p1b = 256;
    if (ws_size < ((size_t)256  * ST + 2320 + 2048) * 4) p1b = 128;
    const int tpb = NTOK / p1b;

    float* partials = ws;
    float* stats    = ws + (size_t)p1b * ST;
    float2* ab      = (float2*)(stats + 2320);

    hipLaunchKernelGGL(k1_stats,   dim3(p1b),     dim3(256), 0, stream, ids, wemb, partials, tpb);
    hipLaunchKernelGGL(k2a_reduce, dim3(10, 32),  dim3(256), 0, stream, partials, p1b);
    hipLaunchKernelGGL(k2b_reduce, dim3(10),      dim3(256), 0, stream, partials, stats);
    hipLaunchKernelGGL(k3_final,   dim3(1),       dim3(128), 0, stream, stats, cent, ab);
    hipLaunchKernelGGL(k4_main,    dim3(128, 8),  dim3(256), 0, stream, ids, wemb, cent, ab, out);
}

// Round 9
// 121.649 us; speedup vs baseline: 1.2517x; 1.2143x over previous
//
#include <hip/hip_runtime.h>

// DPQ embedding, MI355X. N=131072 tokens, EMB=128, D=8 subspaces x SUB=16, K=128 codes.
// Pipeline:
//  k1_stats:  gather x rows, accumulate per-block moment stats (G, Sx, h, Sn, S2)
//  k2a/k2b:   deterministic two-stage tree-reduce of block partials (in-place)
//  k3_final:  stats + centroids -> alpha[k], beta[d][k]  (BN folded into affine score)
//  k4_main:   4 tokens/thread, one d/block, launch_bounds(256,4) pins VGPR<=128
//             -> 4 waves/SIMD (R2's residency). Inner dot uses v_pk_fma_f32
//             (float2 ext-vector + __builtin_elementwise_fma): 8 packed FMA per
//             16-dim dot, halving VALU issue.
// History/model: VALU busy-TIME is ~46us constant across R2/R6/R7/R8; duration
// = busy/VALUBusy%. R2 88us @ 4 waves/SIMD (VGPR 88); R8 115us @ 3 waves/SIMD
// (VGPR 136). R5 proved DS pipe does 8cyc/op when fed (32 waves/CU); at low
// residency it starves (eff. 27cyc/op). VGPR -> waves/SIMD is the master knob;
// pk_fma shrinks the busy-time floor itself.

constexpr int NTOK = 131072;   // 1024*128
constexpr int ST   = 2320;     // stats stride (2312 used, padded)
constexpr float EPS = 0.001f;

typedef float v2f __attribute__((ext_vector_type(2)));

// stats layout: G: d*256 + s*16 + s'  (2048)
//               Sx: 2048 + d*16 + s   (128)
//               h : 2176 + d*16 + s   (128)
//               S2: 2304 + d          (8)    -> 2312 total

__global__ __launch_bounds__(256) void k1_stats(const int* __restrict__ ids,
                                                const float* __restrict__ wemb,
                                                float* __restrict__ partials,
                                                int tpb)
{
    __shared__ float xs[32][132];   // 32 tokens x 128 floats, padded to 132
    __shared__ float nrm[32][8];
    const int t = threadIdx.x;
    const int b = blockIdx.x;

    float g[4][4];
#pragma unroll
    for (int i = 0; i < 4; ++i)
#pragma unroll
        for (int j = 0; j < 4; ++j) g[i][j] = 0.f;
    float sx = 0.f, hh = 0.f, s2 = 0.f;

    const int d_g = t >> 4;                 // t<128: Gram task (d, 4x4 tile)
    const int r0  = ((t >> 2) & 3) << 2;
    const int c0  = (t & 3) << 2;
    const int u   = t & 127;                // t>=128: (d,s) task
    const int d_s = u >> 4;
    const int s_s = u & 15;

    const int nchunks = tpb >> 5;
    for (int ch = 0; ch < nchunks; ++ch) {
        const int n0 = b * tpb + ch * 32;
        // ---- load 32 token rows (coalesced: 32 lanes x float4 = one 512B row) ----
#pragma unroll
        for (int rep = 0; rep < 4; ++rep) {
            int i = t + rep * 256;
            int n = i >> 5, f = i & 31;
            int id = ids[n0 + n];
            float4 v = *(const float4*)(wemb + (size_t)id * 128 + f * 4);
            *(float4*)(&xs[n][f * 4]) = v;
        }
        __syncthreads();
        // ---- per-(n,d) norms: 256 threads = 32x8 ----
        {
            int n = t >> 3, dd = t & 7;
            const float* xp = &xs[n][dd * 16];
            float4 a = *(const float4*)(xp);
            float4 bq = *(const float4*)(xp + 4);
            float4 c = *(const float4*)(xp + 8);
            float4 dq = *(const float4*)(xp + 12);
            float acc = a.x*a.x + a.y*a.y + a.z*a.z + a.w*a.w;
            acc += bq.x*bq.x + bq.y*bq.y + bq.z*bq.z + bq.w*bq.w;
            acc += c.x*c.x + c.y*c.y + c.z*c.z + c.w*c.w;
            acc += dq.x*dq.x + dq.y*dq.y + dq.z*dq.z + dq.w*dq.w;
            nrm[n][dd] = acc;
        }
        __syncthreads();
        // ---- accumulate stats over the chunk ----
        if (t < 128) {
            for (int n = 0; n < 32; ++n) {
                const float* xp = &xs[n][d_g * 16];
                float4 av = *(const float4*)(xp + r0);
                float4 bv = *(const float4*)(xp + c0);
                float aa[4] = {av.x, av.y, av.z, av.w};
                float bb[4] = {bv.x, bv.y, bv.z, bv.w};
#pragma unroll
                for (int i = 0; i < 4; ++i)
#pragma unroll
                    for (int j = 0; j < 4; ++j)
                        g[i][j] = fmaf(aa[i], bb[j], g[i][j]);
            }
        } else {
            for (int n = 0; n < 32; ++n) {
                float xv = xs[n][d_s * 16 + s_s];
                float nv = nrm[n][d_s];
                sx += xv;
                hh = fmaf(nv, xv, hh);
                if (s_s == 0) s2 = fmaf(nv, nv, s2);
            }
        }
        __syncthreads();
    }
    float* pb = partials + (size_t)b * ST;
    if (t < 128) {
        const int base = d_g * 256;
#pragma unroll
        for (int i = 0; i < 4; ++i)
#pragma unroll
            for (int j = 0; j < 4; ++j)
                pb[base + (r0 + i) * 16 + (c0 + j)] = g[i][j];
    } else {
        pb[2048 + d_s * 16 + s_s] = sx;
        pb[2176 + d_s * 16 + s_s] = hh;
        if (s_s == 0) pb[2304 + d_s] = s2;
    }
}

// ---- stage A: fold nb blocks down to 32, in place. grid (10, 32). ----
__global__ __launch_bounds__(256) void k2a_reduce(float* __restrict__ partials, int nb)
{
    const int idx = blockIdx.x * 256 + threadIdx.x;
    if (idx >= 2312) return;
    const int y = blockIdx.y;          // 0..31
    float acc[8] = {0.f, 0.f, 0.f, 0.f, 0.f, 0.f, 0.f, 0.f};
    int b = y;
    while (b + 7 * 32 < nb) {
#pragma unroll
        for (int u = 0; u < 8; ++u)
            acc[u] += partials[(size_t)(b + u * 32) * ST + idx];
        b += 8 * 32;
    }
    while (b < nb) { acc[0] += partials[(size_t)b * ST + idx]; b += 32; }
    float s = ((acc[0] + acc[1]) + (acc[2] + acc[3]))
            + ((acc[4] + acc[5]) + (acc[6] + acc[7]));
    partials[(size_t)y * ST + idx] = s;
}

// ---- stage B: sum the 32 survivors (L2-resident, fully unrolled). grid 10. ----
__global__ __launch_bounds__(256) void k2b_reduce(const float* __restrict__ partials,
                                                  float* __restrict__ stats)
{
    const int idx = blockIdx.x * 256 + threadIdx.x;
    if (idx >= 2312) return;
    float acc[8] = {0.f, 0.f, 0.f, 0.f, 0.f, 0.f, 0.f, 0.f};
#pragma unroll
    for (int j = 0; j < 4; ++j)
#pragma unroll
        for (int u = 0; u < 8; ++u)
            acc[u] += partials[(size_t)(j * 8 + u) * ST + idx];
    stats[idx] = ((acc[0] + acc[1]) + (acc[2] + acc[3]))
               + ((acc[4] + acc[5]) + (acc[6] + acc[7]));
}

__global__ __launch_bounds__(128) void k3_final(const float* __restrict__ stats,
                                                const float* __restrict__ centroids,
                                                float2* __restrict__ ab)
{
    __shared__ float st[2312];
    const int t = threadIdx.x;
    for (int i = t; i < 2312; i += 128) st[i] = stats[i];
    __syncthreads();
    const int k = t;   // 128 threads, one per code

    double Sn[8], Sn_tot = 0.0, S2_tot = 0.0;
#pragma unroll
    for (int d = 0; d < 8; ++d) {
        double s = 0.0;
        for (int ss = 0; ss < 16; ++ss) s += (double)st[d * 256 + ss * 17];
        Sn[d] = s; Sn_tot += s;
        S2_tot += (double)st[2304 + d];
    }
    double sr = -Sn_tot, sr2 = S2_tot;
    double ncd[8];
    for (int d = 0; d < 8; ++d) {
        const float* cp = centroids + d * 2048 + k * 16;
        float cv[16];
#pragma unroll
        for (int s = 0; s < 16; ++s) cv[s] = cp[s];
        double nc = 0, cdSx = 0, ch = 0, cGc = 0;
        for (int s = 0; s < 16; ++s) {
            nc   += (double)cv[s] * cv[s];
            cdSx += (double)cv[s] * st[2048 + d * 16 + s];
            ch   += (double)cv[s] * st[2176 + d * 16 + s];
            double rd = 0;
            for (int s2i = 0; s2i < 16; ++s2i)
                rd += (double)st[d * 256 + s * 16 + s2i] * cv[s2i];
            cGc += (double)cv[s] * rd;
        }
        ncd[d] = nc;
        sr  += 2.0 * cdSx - (double)NTOK * nc;
        sr2 += 4.0 * cGc + (double)NTOK * nc * nc + 2.0 * nc * Sn[d]
               - 4.0 * ch - 4.0 * nc * cdSx;
    }
    const double M = (double)NTOK * 8.0;
    double mean = sr / M;
    double var  = sr2 / M - mean * mean;
    float alpha = (float)(1.0 / sqrt(var + (double)EPS));
#pragma unroll
    for (int d = 0; d < 8; ++d) {
        float beta = (float)((double)alpha * (-ncd[d] - mean));
        ab[d * 128 + k] = make_float2(2.f * alpha, beta);
    }
}

// 4 tokens/thread, one d per blockIdx.y, 256-thread blocks.
// launch_bounds(256,4): VGPR cap 128 -> 4 waves/SIMD guaranteed (state ~120
// live, so little/no spill -- unlike R3's cap-64 AGPR-shuttle disaster).
// Dot products via v_pk_fma_f32 (packed fp32): 8 pk_fma per 16-dim dot.
__global__ __launch_bounds__(256, 4) void k4_main(const int* __restrict__ ids,
                                                  const float* __restrict__ wemb,
                                                  const float* __restrict__ centroids,
                                                  const float2* __restrict__ ab,
                                                  float* __restrict__ out)
{
    __shared__ float  cs[128 * 16];   // 8KB: centroids for this d
    __shared__ float2 gbs[128];       // (2*alpha, beta)

    const int t = threadIdx.x;        // 0..255
    const int d = blockIdx.y;
    const float* cd = centroids + (size_t)d * 2048;

    // stage: 2048 floats = 512 float4 -> 2 per thread; gb for t<128
#pragma unroll
    for (int i = 0; i < 2; ++i)
        ((float4*)cs)[t + i * 256] = ((const float4*)cd)[t + i * 256];
    if (t < 128) gbs[t] = ab[(size_t)d * 128 + t];

    const int nbase = blockIdx.x * 1024 + t;   // 4 tokens, stride 256
    v2f x[4][8];                       // token x as 8 packed pairs
    v2f nxv[4];                        // (-norm/2, 0) -> first pk_fma addend
    float best[4];
    int   code[4];
#pragma unroll
    for (int j = 0; j < 4; ++j) {
        const int n = nbase + j * 256;
        const float* xp = wemb + (size_t)ids[n] * 128 + d * 16;
#pragma unroll
        for (int q = 0; q < 4; ++q) {
            float4 v = *(const float4*)(xp + q * 4);
            x[j][q * 2]     = (v2f){v.x, v.y};
            x[j][q * 2 + 1] = (v2f){v.z, v.w};
        }
        float s = 0.f;
#pragma unroll
        for (int q = 0; q < 8; ++q)
            s += x[j][q][0] * x[j][q][0] + x[j][q][1] * x[j][q][1];
        nxv[j] = (v2f){-0.5f * s, 0.f}; // score = 2a*(dot - nx/2) + beta
        best[j] = -3.4e38f;
        code[j] = 0;
    }

    __syncthreads();

#pragma unroll 2
    for (int k = 0; k < 128; ++k) {
        // wave-uniform broadcast reads: 4x ds_read_b128 + 1 ds_read_b64.
        // b128 lands in even-aligned reg quads -> (x,y)/(z,w) are native
        // v2f pairs, zero repack movs.
        const float4 c0 = *(const float4*)(&cs[k * 16 + 0]);
        const float4 c1 = *(const float4*)(&cs[k * 16 + 4]);
        const float4 c2 = *(const float4*)(&cs[k * 16 + 8]);
        const float4 c3 = *(const float4*)(&cs[k * 16 + 12]);
        const float2 g  = gbs[k];
        const v2f cc0 = (v2f){c0.x, c0.y}, cc1 = (v2f){c0.z, c0.w};
        const v2f cc2 = (v2f){c1.x, c1.y}, cc3 = (v2f){c1.z, c1.w};
        const v2f cc4 = (v2f){c2.x, c2.y}, cc5 = (v2f){c2.z, c2.w};
        const v2f cc6 = (v2f){c3.x, c3.y}, cc7 = (v2f){c3.z, c3.w};
#pragma unroll
        for (int j = 0; j < 4; ++j) {
            v2f a = __builtin_elementwise_fma(cc0, x[j][0], nxv[j]);
            a = __builtin_elementwise_fma(cc1, x[j][1], a);
            a = __builtin_elementwise_fma(cc2, x[j][2], a);
            a = __builtin_elementwise_fma(cc3, x[j][3], a);
            a = __builtin_elementwise_fma(cc4, x[j][4], a);
            a = __builtin_elementwise_fma(cc5, x[j][5], a);
            a = __builtin_elementwise_fma(cc6, x[j][6], a);
            a = __builtin_elementwise_fma(cc7, x[j][7], a);
            float acc = a[0] + a[1];
            float sc = fmaf(g.x, acc, g.y);
            bool p = sc > best[j];         // strict > keeps FIRST max (argmax tie rule)
            best[j] = p ? sc : best[j];
            code[j] = p ? k : code[j];
        }
    }

#pragma unroll
    for (int j = 0; j < 4; ++j) {
        const int n = nbase + j * 256;
        const float* cw = &cs[code[j] * 16];   // LDS, divergent (epilogue only)
        float* op = out + (size_t)n * 128 + d * 16;
#pragma unroll
        for (int q = 0; q < 4; ++q) {
            float4 cv = *(const float4*)(cw + q * 4);
            float x0 = x[j][q * 2][0],     x1 = x[j][q * 2][1];
            float x2 = x[j][q * 2 + 1][0], x3 = x[j][q * 2 + 1][1];
            float4 o;
            // match reference: out = x + (c - x) in fp32 (not just c)
            o.x = x0 + (cv.x - x0);
            o.y = x1 + (cv.y - x1);
            o.z = x2 + (cv.z - x2);
            o.w = x3 + (cv.w - x3);
            *(float4*)(op + q * 4) = o;
        }
    }
}

extern "C" void kernel_launch(void* const* d_in, const int* in_sizes, int n_in,
                              void* d_out, int out_size, void* d_ws, size_t ws_size,
                              hipStream_t stream)
{
    const int* ids    = (const int*)d_in[0];
    const float* wemb = (const float*)d_in[1];
    const float* cent = (const float*)d_in[2];
    float* out = (float*)d_out;
    float* ws  = (float*)d_ws;

    // choose pass-1 block count by available workspace
    int p1b = 1024;
    if (ws_size < ((size_t)1024 * ST + 2320 + 2048) * 4) p1b = 512;
    if (ws_size < ((size_t)512  * ST + 2320 + 2048) * 4) p1b = 256;
    if (ws_size < ((size_t)256  * ST + 2320 + 2048) * 4) p1b = 128;
    const int tpb = NTOK / p1b;

    float* partials = ws;
    float* stats    = ws + (size_t)p1b * ST;
    float2* ab      = (float2*)(stats + 2320);

    hipLaunchKernelGGL(k1_stats,   dim3(p1b),     dim3(256), 0, stream, ids, wemb, partials, tpb);
    hipLaunchKernelGGL(k2a_reduce, dim3(10, 32),  dim3(256), 0, stream, partials, p1b);
    hipLaunchKernelGGL(k2b_reduce, dim3(10),      dim3(256), 0, stream, partials, stats);
    hipLaunchKernelGGL(k3_final,   dim3(1),       dim3(128), 0, stream, stats, cent, ab);
    hipLaunchKernelGGL(k4_main,    dim3(128, 8),  dim3(256), 0, stream, ids, wemb, cent, ab, out);
}